// Round 20
// baseline (999.735 us; speedup 1.0000x reference)
//
#include <hip/hip_runtime.h>

#define Hdim 256
static const int E_N  = 260640;
static const int NG_N = 65160;
static const int NM_N = 40962;
static const int NB_E = (E_N + 127) / 128;        // 2037 E' blocks
static const int RT_N = NB_E * 8;                 // 16296 rowtiles (16 rows each)
static const int GB_N = RT_N / 4;                 // 4074 G blocks (64 rows each)

typedef __attribute__((ext_vector_type(8))) __bf16 bf16x8;
typedef __attribute__((ext_vector_type(8))) unsigned short u16x8;
typedef __attribute__((ext_vector_type(4))) float f32x4;

__device__ __forceinline__ unsigned short f2bf(float f) {
  unsigned u = __float_as_uint(f);
  u = (u + 0x7FFFu + ((u >> 16) & 1u)) >> 16;
  return (unsigned short)u;
}
__device__ __forceinline__ float bf2f(unsigned short h) {
  return __uint_as_float((unsigned)h << 16);
}
struct BfPair { unsigned short hi, lo; };
__device__ __forceinline__ BfPair split2(float f) {
  BfPair r;
  r.hi = f2bf(f);
  r.lo = f2bf(f - bf2f(r.hi));
  return r;
}
__device__ __forceinline__ BfPair split2t(float f) {
  unsigned u = __float_as_uint(f);
  BfPair r;
  r.hi = (unsigned short)(u >> 16);
  r.lo = f2bf(f - __uint_as_float(u & 0xffff0000u));
  return r;
}
__device__ __forceinline__ int hswz(int row) {
  return ((row & 7) << 3) ^ (((row >> 2) & 3) << 4);
}
__device__ __forceinline__ void bar_lds() {
  asm volatile("s_waitcnt lgkmcnt(0)" ::: "memory");
  __builtin_amdgcn_s_barrier();
}

// W [K][N=256] f32 -> fragment-major split-bf16 (R12-verified)
__global__ void wfrag_kernel(const float* __restrict__ W,
                             unsigned short* __restrict__ Fh,
                             unsigned short* __restrict__ Fl, int K, int N) {
  int i = blockIdx.x * 256 + threadIdx.x;
  if (i >= K * N) return;
  int k = i / N;
  int col = i - k * N;
  BfPair p = split2(W[i]);
  int t = k >> 5, rem = k & 31;
  int lg = rem >> 3, j = rem & 7;
  int cb = col >> 4, lr = col & 15;
  long o = ((long)(t * 16 + cb) * 64 + (lg * 16 + lr)) * 8 + j;
  Fh[o] = p.hi;
  Fl[o] = p.lo;
}

// ============================================================================
// G: gather cat=[g2m, grid[src], mesh[dst]] -> bf16-hi, packed A-fragment-major
// catF[((rowtile*24 + t)*64 + lane)*8 + j] = cat[rowtile*16 + (lane&15)]
//                                               [t*32 + (lane>>4)*8 + j]
// ============================================================================
__global__ __launch_bounds__(256, 4)
void gather_frag(const float* __restrict__ g2m, const float* __restrict__ gridf,
                 const float* __restrict__ meshf, const int* __restrict__ src,
                 const int* __restrict__ dst, int M,
                 unsigned short* __restrict__ catF) {
  __shared__ unsigned short tile[64][72];
  const int tid = threadIdx.x;
  const int w = tid >> 6;
  const int l = tid & 63;
  const int lr = l & 15;
  const int lg = l >> 4;
  const long blockRow = (long)blockIdx.x * 64;
  long growc = blockRow + l;
  if (growc >= M) growc = M - 1;
  const float* rp0 = g2m + growc * Hdim;
  const float* rp1 = gridf + (long)src[growc] * Hdim;
  const float* rp2 = meshf + (long)dst[growc] * Hdim;

  for (int m = 0; m < 12; ++m) {
    const int seg = m >> 2;
    const float* rp = seg == 0 ? rp0 : (seg == 1 ? rp1 : rp2);
    const float* p = rp + (m & 3) * 64 + w * 16;
    float4 v0 = *(const float4*)p;
    float4 v1 = *(const float4*)(p + 4);
    float4 v2 = *(const float4*)(p + 8);
    float4 v3 = *(const float4*)(p + 12);
    __syncthreads();  // previous iteration's frag reads done
    {
      float in[16] = {v0.x, v0.y, v0.z, v0.w, v1.x, v1.y, v1.z, v1.w,
                      v2.x, v2.y, v2.z, v2.w, v3.x, v3.y, v3.z, v3.w};
      u16x8 t0, t1;
#pragma unroll
      for (int j = 0; j < 8; ++j) {
        t0[j] = f2bf(in[j]);
        t1[j] = f2bf(in[j + 8]);
      }
      *(u16x8*)&tile[l][w * 16]     = t0;
      *(u16x8*)&tile[l][w * 16 + 8] = t1;
    }
    __syncthreads();
    // wave w emits fragments for rowtile (blockIdx*4 + w), both k-steps of macro m
    const long rowtile = (long)blockIdx.x * 4 + w;
#pragma unroll
    for (int tt = 0; tt < 2; ++tt) {
      const int t = m * 2 + tt;
      u16x8 v = *(const u16x8*)&tile[w * 16 + lr][tt * 32 + lg * 8];
      *(u16x8*)&catF[((rowtile * 24 + t) * 64 + l) * 8] = v;
    }
  }
}

// ============================================================================
// E': edge GEMM from pre-packed catF. 128 rows/block, 512 thr (8 waves),
// wave w owns cols [w*32, w*32+32). No A-LDS, no barriers in layer-1 K-loop.
// ============================================================================
struct ESMem {
  unsigned short hh[128 * 256];   // 64 KB, XOR-swizzled
  float lnp[8][128][2];           // 8 KB
};

__global__ __launch_bounds__(512, 2)
void edge_gemm(const unsigned short* __restrict__ catF, int M,
               const unsigned short* __restrict__ W1Fh, const unsigned short* __restrict__ W1Fl,
               const float* __restrict__ b1,
               const unsigned short* __restrict__ W2Fh, const unsigned short* __restrict__ W2Fl,
               const float* __restrict__ b2,
               const float* __restrict__ gamma, const float* __restrict__ beta,
               float* __restrict__ agg, const int* __restrict__ scat) {
  __shared__ ESMem sm;
  const int tid = threadIdx.x;
  const int w = tid >> 6;        // 0..7
  const int l = tid & 63;
  const int lr = l & 15;
  const int lg = l >> 4;
  const int colbase = w * 32 + lr;
  const long blockRow = (long)blockIdx.x * 128;
  const long rt0 = (long)blockIdx.x * 8;

  auto loadAF = [&](int t, bf16x8* af) {
#pragma unroll
    for (int rb = 0; rb < 8; ++rb)
      af[rb] = *(const bf16x8*)(catF + (((rt0 + rb) * 24 + t) * 64 + l) * 8);
  };
  auto loadB1 = [&](int t, bf16x8* bh, bf16x8* bl) {
#pragma unroll
    for (int n = 0; n < 2; ++n) {
      const long o = ((long)(t * 16 + w * 2 + n) * 64 + l) * 8;
      bh[n] = *(const bf16x8*)(W1Fh + o);
      bl[n] = *(const bf16x8*)(W1Fl + o);
    }
  };

  // ---------------- layer 1: barrier-free K-loop (24 steps) ----------------
  f32x4 acc[8][2] = {};
  bf16x8 afc[8], afn[8], bhc[2], blc[2], bhn[2], bln[2];
  loadAF(0, afc);
  loadB1(0, bhc, blc);
  for (int t = 0; t < 24; ++t) {
    const int tn = t + 1 < 24 ? t + 1 : 23;
    loadAF(tn, afn);
    loadB1(tn, bhn, bln);
    __builtin_amdgcn_s_setprio(1);
#pragma unroll
    for (int rb = 0; rb < 8; ++rb)
#pragma unroll
      for (int n = 0; n < 2; ++n) {
        acc[rb][n] = __builtin_amdgcn_mfma_f32_16x16x32_bf16(afc[rb], bhc[n], acc[rb][n], 0, 0, 0);
        acc[rb][n] = __builtin_amdgcn_mfma_f32_16x16x32_bf16(afc[rb], blc[n], acc[rb][n], 0, 0, 0);
      }
    __builtin_amdgcn_s_setprio(0);
#pragma unroll
    for (int rb = 0; rb < 8; ++rb) afc[rb] = afn[rb];
#pragma unroll
    for (int n = 0; n < 2; ++n) { bhc[n] = bhn[n]; blc[n] = bln[n]; }
  }

  // B2(0) prefetch early
  bf16x8 b2hc[2], b2lc[2];
#pragma unroll
  for (int n = 0; n < 2; ++n) {
    const long o = ((long)(w * 2 + n) * 64 + l) * 8;
    b2hc[n] = *(const bf16x8*)(W2Fh + o);
    b2lc[n] = *(const bf16x8*)(W2Fl + o);
  }

  // ---------------- bias1 + SiLU -> h ----------------
  float bb1[2];
#pragma unroll
  for (int n = 0; n < 2; ++n) bb1[n] = b1[colbase + n * 16];
#pragma unroll
  for (int rb = 0; rb < 8; ++rb) {
#pragma unroll
    for (int n = 0; n < 2; ++n) {
      const int col = colbase + n * 16;
#pragma unroll
      for (int r = 0; r < 4; ++r) {
        const int row = rb * 16 + lg * 4 + r;
        float v = acc[rb][n][r] + bb1[n];
        v = v / (1.0f + __expf(-v));
        sm.hh[row * 256 + (col ^ hswz(row))] = f2bf(v);
      }
    }
  }
  bar_lds();

  // ---------------- layer 2: h @ W2 (2-product) ----------------
  f32x4 acc2[8][2] = {};
  for (int ks = 0; ks < 8; ++ks) {
    const int kn = (ks + 1 < 8) ? ks + 1 : ks;
    bf16x8 b2hn[2], b2ln[2];
#pragma unroll
    for (int n = 0; n < 2; ++n) {
      const long o = ((long)(kn * 16 + w * 2 + n) * 64 + l) * 8;
      b2hn[n] = *(const bf16x8*)(W2Fh + o);
      b2ln[n] = *(const bf16x8*)(W2Fl + o);
    }
    __builtin_amdgcn_s_setprio(1);
#pragma unroll
    for (int rb = 0; rb < 8; ++rb) {
      const int row = rb * 16 + lr;
      bf16x8 ah = *(const bf16x8*)&sm.hh[row * 256 + ((ks * 32 + lg * 8) ^ hswz(row))];
#pragma unroll
      for (int n = 0; n < 2; ++n) {
        acc2[rb][n] = __builtin_amdgcn_mfma_f32_16x16x32_bf16(ah, b2hc[n], acc2[rb][n], 0, 0, 0);
        acc2[rb][n] = __builtin_amdgcn_mfma_f32_16x16x32_bf16(ah, b2lc[n], acc2[rb][n], 0, 0, 0);
      }
    }
    __builtin_amdgcn_s_setprio(0);
#pragma unroll
    for (int n = 0; n < 2; ++n) { b2hc[n] = b2hn[n]; b2lc[n] = b2ln[n]; }
  }

  // ---------------- LayerNorm (two-pass) + atomic scatter ----------------
  float bb2[2], gmv[2], btv[2];
#pragma unroll
  for (int n = 0; n < 2; ++n) {
    const int c = colbase + n * 16;
    bb2[n] = b2[c];
    gmv[n] = gamma[c];
    btv[n] = beta[c];
  }
  float psum[32];
#pragma unroll
  for (int rb = 0; rb < 8; ++rb)
#pragma unroll
    for (int r = 0; r < 4; ++r) {
      float s = 0.f;
#pragma unroll
      for (int n = 0; n < 2; ++n) s += acc2[rb][n][r] + bb2[n];
      psum[rb * 4 + r] = s;
    }
#pragma unroll
  for (int i = 0; i < 32; ++i) {
    psum[i] += __shfl_xor(psum[i], 1, 64);
    psum[i] += __shfl_xor(psum[i], 2, 64);
    psum[i] += __shfl_xor(psum[i], 4, 64);
    psum[i] += __shfl_xor(psum[i], 8, 64);
  }
  if (lr == 0) {
#pragma unroll
    for (int rb = 0; rb < 8; ++rb)
#pragma unroll
      for (int r = 0; r < 4; ++r)
        sm.lnp[w][rb * 16 + lg * 4 + r][0] = psum[rb * 4 + r];
  }
  __syncthreads();
  float mu[32];
#pragma unroll
  for (int rb = 0; rb < 8; ++rb)
#pragma unroll
    for (int r = 0; r < 4; ++r) {
      const int row = rb * 16 + lg * 4 + r;
      float s = 0.f;
#pragma unroll
      for (int q = 0; q < 8; ++q) s += sm.lnp[q][row][0];
      mu[rb * 4 + r] = s * (1.0f / 256.0f);
    }
  float psq[32];
#pragma unroll
  for (int rb = 0; rb < 8; ++rb)
#pragma unroll
    for (int r = 0; r < 4; ++r) {
      float s = 0.f;
#pragma unroll
      for (int n = 0; n < 2; ++n) {
        const float d = acc2[rb][n][r] + bb2[n] - mu[rb * 4 + r];
        s += d * d;
      }
      psq[rb * 4 + r] = s;
    }
#pragma unroll
  for (int i = 0; i < 32; ++i) {
    psq[i] += __shfl_xor(psq[i], 1, 64);
    psq[i] += __shfl_xor(psq[i], 2, 64);
    psq[i] += __shfl_xor(psq[i], 4, 64);
    psq[i] += __shfl_xor(psq[i], 8, 64);
  }
  if (lr == 0) {
#pragma unroll
    for (int rb = 0; rb < 8; ++rb)
#pragma unroll
      for (int r = 0; r < 4; ++r)
        sm.lnp[w][rb * 16 + lg * 4 + r][1] = psq[rb * 4 + r];
  }
  __syncthreads();
#pragma unroll
  for (int rb = 0; rb < 8; ++rb) {
#pragma unroll
    for (int r = 0; r < 4; ++r) {
      const int row = rb * 16 + lg * 4 + r;
      const long grow = blockRow + row;
      if (grow >= M) continue;
      float sq = 0.f;
#pragma unroll
      for (int q = 0; q < 8; ++q) sq += sm.lnp[q][row][1];
      const float var = sq * (1.0f / 256.0f);
      const float rstd = 1.0f / sqrtf(var + 1e-5f);
      const float m = mu[rb * 4 + r];
      const int d = scat[grow];
      float* ap = agg + (long)d * Hdim;
#pragma unroll
      for (int n = 0; n < 2; ++n) {
        const int c = colbase + n * 16;
        atomicAdd(ap + c, (acc2[rb][n][r] + bb2[n] - m) * rstd * gmv[n] + btv[n]);
      }
    }
  }
}

// ============================================================================
// R17-verified fused MLP for grid/mesh node paths (3-product, 256 thr)
// ============================================================================
template <bool A3>
struct SMem {
  union {
    unsigned short ahi[2][64][72];
    float lnp[4][64][2];
  } u;
  unsigned short alo[2][64][72];
  unsigned short hh[64 * 256];
};

template <int NSEG>
__launch_bounds__(256, 2)
__global__ void mlp_mfma(
    const float* s0, const float* s1,
    const int* __restrict__ i1, int M,
    const unsigned short* __restrict__ W1Fh, const unsigned short* __restrict__ W1Fl,
    const float* __restrict__ b1,
    const unsigned short* __restrict__ W2Fh, const unsigned short* __restrict__ W2Fl,
    const float* __restrict__ b2,
    const float* __restrict__ gamma, const float* __restrict__ beta,
    const float* residual, float* outp) {
  constexpr int K1 = NSEG * 256;
  constexpr int NT = K1 / 32;
  constexpr int NU = K1 / 64;
  __shared__ SMem<true> sm;

  const int tid = threadIdx.x;
  const int w = tid >> 6;
  const int l = tid & 63;
  const int lr = l & 15;
  const int lg = l >> 4;
  const int colbase = w * 64 + lr;
  const long blockRow = (long)blockIdx.x * 64;

  const long grow_s = blockRow + l;
  const long growc = grow_s < M ? grow_s : (long)(M - 1);
  const float* rp0 = s0 + growc * Hdim;
  const float* rp1 = nullptr;
  if (NSEG >= 2) rp1 = s1 + (long)(i1 ? i1[growc] : (int)growc) * Hdim;

  auto aptr = [&](int m) -> const float* {
    const int seg = m >> 2;
    const float* rp = (NSEG >= 2 && seg == 1) ? rp1 : rp0;
    return rp + (m & 3) * 64 + w * 16;
  };
  auto loadA = [&](int m, float4* v) {
    const float* p = aptr(m);
#pragma unroll
    for (int i = 0; i < 4; ++i) v[i] = *(const float4*)(p + i * 4);
  };
  auto stageA = [&](int buf, const float4* v) {
    float in[16] = {v[0].x, v[0].y, v[0].z, v[0].w, v[1].x, v[1].y, v[1].z, v[1].w,
                    v[2].x, v[2].y, v[2].z, v[2].w, v[3].x, v[3].y, v[3].z, v[3].w};
    u16x8 th0, tl0, th1, tl1;
#pragma unroll
    for (int j = 0; j < 8; ++j) {
      BfPair p0 = split2t(in[j]);
      th0[j] = p0.hi; tl0[j] = p0.lo;
      BfPair p1 = split2t(in[j + 8]);
      th1[j] = p1.hi; tl1[j] = p1.lo;
    }
    *(u16x8*)&sm.u.ahi[buf][l][w * 16]     = th0;
    *(u16x8*)&sm.u.ahi[buf][l][w * 16 + 8] = th1;
    *(u16x8*)&sm.alo[buf][l][w * 16]       = tl0;
    *(u16x8*)&sm.alo[buf][l][w * 16 + 8]   = tl1;
  };
  auto loadB1 = [&](int t, bf16x8* bh, bf16x8* bl) {
#pragma unroll
    for (int n = 0; n < 4; ++n) {
      const long o = ((long)(t * 16 + w * 4 + n) * 64 + l) * 8;
      bh[n] = *(const bf16x8*)(W1Fh + o);
      bl[n] = *(const bf16x8*)(W1Fl + o);
    }
  };

  f32x4 acc[4][4] = {};
  {
    float4 v[4];
    loadA(0, v);
    stageA(0, v);
  }
  float4 va[4], vb[4];
  loadA(1 < NU ? 1 : NU - 1, va);
  bf16x8 bhc[4], blc[4];
  loadB1(0, bhc, blc);

  for (int u = 0; u < NU; ++u) {
    bar_lds();
    loadA(u + 2 < NU ? u + 2 : NU - 1, vb);
    bf16x8 bhn[4], bln[4];
    loadB1(2 * u + 1 < NT ? 2 * u + 1 : NT - 1, bhn, bln);
    bf16x8 ah[4], al[4];
#pragma unroll
    for (int rb = 0; rb < 4; ++rb) {
      ah[rb] = *(const bf16x8*)&sm.u.ahi[u & 1][rb * 16 + lr][lg * 8];
      al[rb] = *(const bf16x8*)&sm.alo[u & 1][rb * 16 + lr][lg * 8];
    }
    __builtin_amdgcn_s_setprio(1);
#pragma unroll
    for (int rb = 0; rb < 4; ++rb)
#pragma unroll
      for (int n = 0; n < 4; ++n) {
        acc[rb][n] = __builtin_amdgcn_mfma_f32_16x16x32_bf16(ah[rb], bhc[n], acc[rb][n], 0, 0, 0);
        acc[rb][n] = __builtin_amdgcn_mfma_f32_16x16x32_bf16(ah[rb], blc[n], acc[rb][n], 0, 0, 0);
        acc[rb][n] = __builtin_amdgcn_mfma_f32_16x16x32_bf16(al[rb], bhc[n], acc[rb][n], 0, 0, 0);
      }
    __builtin_amdgcn_s_setprio(0);
    bf16x8 bh2[4], bl2[4];
    loadB1(2 * u + 2 < NT ? 2 * u + 2 : NT - 1, bh2, bl2);
#pragma unroll
    for (int rb = 0; rb < 4; ++rb) {
      ah[rb] = *(const bf16x8*)&sm.u.ahi[u & 1][rb * 16 + lr][32 + lg * 8];
      al[rb] = *(const bf16x8*)&sm.alo[u & 1][rb * 16 + lr][32 + lg * 8];
    }
    __builtin_amdgcn_s_setprio(1);
#pragma unroll
    for (int rb = 0; rb < 4; ++rb)
#pragma unroll
      for (int n = 0; n < 4; ++n) {
        acc[rb][n] = __builtin_amdgcn_mfma_f32_16x16x32_bf16(ah[rb], bhn[n], acc[rb][n], 0, 0, 0);
        acc[rb][n] = __builtin_amdgcn_mfma_f32_16x16x32_bf16(ah[rb], bln[n], acc[rb][n], 0, 0, 0);
        acc[rb][n] = __builtin_amdgcn_mfma_f32_16x16x32_bf16(al[rb], bhn[n], acc[rb][n], 0, 0, 0);
      }
    __builtin_amdgcn_s_setprio(0);
    if (u + 1 < NU) stageA((u + 1) & 1, va);
#pragma unroll
    for (int i = 0; i < 4; ++i) va[i] = vb[i];
#pragma unroll
    for (int n = 0; n < 4; ++n) { bhc[n] = bh2[n]; blc[n] = bl2[n]; }
  }

  bf16x8 b2hc[4], b2lc[4];
#pragma unroll
  for (int n = 0; n < 4; ++n) {
    const long o = ((long)(w * 4 + n) * 64 + l) * 8;
    b2hc[n] = *(const bf16x8*)(W2Fh + o);
    b2lc[n] = *(const bf16x8*)(W2Fl + o);
  }

  float bb1[4];
#pragma unroll
  for (int n = 0; n < 4; ++n) bb1[n] = b1[colbase + n * 16];
#pragma unroll
  for (int rb = 0; rb < 4; ++rb) {
#pragma unroll
    for (int n = 0; n < 4; ++n) {
      const int col = colbase + n * 16;
#pragma unroll
      for (int r = 0; r < 4; ++r) {
        const int row = rb * 16 + lg * 4 + r;
        float v = acc[rb][n][r] + bb1[n];
        v = v / (1.0f + __expf(-v));
        sm.hh[row * 256 + (col ^ hswz(row))] = f2bf(v);
      }
    }
  }
  bar_lds();

  f32x4 acc2[4][4] = {};
  for (int ks = 0; ks < 8; ++ks) {
    const int kn = (ks + 1 < 8) ? ks + 1 : ks;
    bf16x8 b2hn[4], b2ln[4];
#pragma unroll
    for (int n = 0; n < 4; ++n) {
      const long o = ((long)(kn * 16 + w * 4 + n) * 64 + l) * 8;
      b2hn[n] = *(const bf16x8*)(W2Fh + o);
      b2ln[n] = *(const bf16x8*)(W2Fl + o);
    }
    bf16x8 ah[4];
#pragma unroll
    for (int rb = 0; rb < 4; ++rb) {
      const int row = rb * 16 + lr;
      ah[rb] = *(const bf16x8*)&sm.hh[row * 256 + ((ks * 32 + lg * 8) ^ hswz(row))];
    }
    __builtin_amdgcn_s_setprio(1);
#pragma unroll
    for (int rb = 0; rb < 4; ++rb)
#pragma unroll
      for (int n = 0; n < 4; ++n) {
        acc2[rb][n] = __builtin_amdgcn_mfma_f32_16x16x32_bf16(ah[rb], b2hc[n], acc2[rb][n], 0, 0, 0);
        acc2[rb][n] = __builtin_amdgcn_mfma_f32_16x16x32_bf16(ah[rb], b2lc[n], acc2[rb][n], 0, 0, 0);
      }
    __builtin_amdgcn_s_setprio(0);
#pragma unroll
    for (int n = 0; n < 4; ++n) { b2hc[n] = b2hn[n]; b2lc[n] = b2ln[n]; }
  }
  __syncthreads();

  float bb2[4], gmv[4], btv[4];
#pragma unroll
  for (int n = 0; n < 4; ++n) {
    const int c = colbase + n * 16;
    bb2[n] = b2[c];
    gmv[n] = gamma[c];
    btv[n] = beta[c];
  }
  float psum[16];
#pragma unroll
  for (int rb = 0; rb < 4; ++rb)
#pragma unroll
    for (int r = 0; r < 4; ++r) {
      float s = 0.f;
#pragma unroll
      for (int n = 0; n < 4; ++n) s += acc2[rb][n][r] + bb2[n];
      psum[rb * 4 + r] = s;
    }
#pragma unroll
  for (int i = 0; i < 16; ++i) {
    psum[i] += __shfl_xor(psum[i], 1, 64);
    psum[i] += __shfl_xor(psum[i], 2, 64);
    psum[i] += __shfl_xor(psum[i], 4, 64);
    psum[i] += __shfl_xor(psum[i], 8, 64);
  }
  if (lr == 0) {
#pragma unroll
    for (int rb = 0; rb < 4; ++rb)
#pragma unroll
      for (int r = 0; r < 4; ++r)
        sm.u.lnp[w][rb * 16 + lg * 4 + r][0] = psum[rb * 4 + r];
  }
  __syncthreads();
  float mu[16];
#pragma unroll
  for (int rb = 0; rb < 4; ++rb)
#pragma unroll
    for (int r = 0; r < 4; ++r) {
      const int row = rb * 16 + lg * 4 + r;
      mu[rb * 4 + r] = (sm.u.lnp[0][row][0] + sm.u.lnp[1][row][0] +
                        sm.u.lnp[2][row][0] + sm.u.lnp[3][row][0]) * (1.0f / 256.0f);
    }
  float psq[16];
#pragma unroll
  for (int rb = 0; rb < 4; ++rb)
#pragma unroll
    for (int r = 0; r < 4; ++r) {
      float s = 0.f;
#pragma unroll
      for (int n = 0; n < 4; ++n) {
        const float d = acc2[rb][n][r] + bb2[n] - mu[rb * 4 + r];
        s += d * d;
      }
      psq[rb * 4 + r] = s;
    }
#pragma unroll
  for (int i = 0; i < 16; ++i) {
    psq[i] += __shfl_xor(psq[i], 1, 64);
    psq[i] += __shfl_xor(psq[i], 2, 64);
    psq[i] += __shfl_xor(psq[i], 4, 64);
    psq[i] += __shfl_xor(psq[i], 8, 64);
  }
  if (lr == 0) {
#pragma unroll
    for (int rb = 0; rb < 4; ++rb)
#pragma unroll
      for (int r = 0; r < 4; ++r)
        sm.u.lnp[w][rb * 16 + lg * 4 + r][1] = psq[rb * 4 + r];
  }
  __syncthreads();
#pragma unroll
  for (int rb = 0; rb < 4; ++rb) {
#pragma unroll
    for (int r = 0; r < 4; ++r) {
      const int row = rb * 16 + lg * 4 + r;
      const long grow = blockRow + row;
      if (grow >= M) continue;
      const float var = (sm.u.lnp[0][row][1] + sm.u.lnp[1][row][1] +
                         sm.u.lnp[2][row][1] + sm.u.lnp[3][row][1]) * (1.0f / 256.0f);
      const float rstd = 1.0f / sqrtf(var + 1e-5f);
      const float m = mu[rb * 4 + r];
      const long o = grow * Hdim;
#pragma unroll
      for (int n = 0; n < 4; ++n) {
        const int c = colbase + n * 16;
        outp[o + c] = (acc2[rb][n][r] + bb2[n] - m) * rstd * gmv[n] + btv[n] + residual[o + c];
      }
    }
  }
}

extern "C" void kernel_launch(void* const* d_in, const int* in_sizes, int n_in,
                              void* d_out, int out_size, void* d_ws, size_t ws_size,
                              hipStream_t stream) {
  const float* g2m   = (const float*)d_in[0];
  const float* gridf = (const float*)d_in[1];
  const float* meshf = (const float*)d_in[2];
  const int*   src   = (const int*)d_in[3];
  const int*   dst   = (const int*)d_in[4];
  const float* eW1 = (const float*)d_in[5];  const float* eb1 = (const float*)d_in[6];
  const float* eW2 = (const float*)d_in[7];  const float* eb2 = (const float*)d_in[8];
  const float* eg  = (const float*)d_in[9];  const float* ebt = (const float*)d_in[10];
  const float* sW1 = (const float*)d_in[11]; const float* sb1 = (const float*)d_in[12];
  const float* sW2 = (const float*)d_in[13]; const float* sb2 = (const float*)d_in[14];
  const float* sg  = (const float*)d_in[15]; const float* sbt = (const float*)d_in[16];
  const float* dW1 = (const float*)d_in[17]; const float* db1 = (const float*)d_in[18];
  const float* dW2 = (const float*)d_in[19]; const float* db2 = (const float*)d_in[20];
  const float* dg  = (const float*)d_in[21]; const float* dbt = (const float*)d_in[22];

  float* out_grid = (float*)d_out;
  float* out_mesh = out_grid + (long)NG_N * Hdim;

  unsigned short* p = (unsigned short*)d_ws;
  unsigned short* eW1Fh = p; p += 768 * 256;  unsigned short* eW1Fl = p; p += 768 * 256;
  unsigned short* eW2Fh = p; p += 256 * 256;  unsigned short* eW2Fl = p; p += 256 * 256;
  unsigned short* sW1Fh = p; p += 256 * 256;  unsigned short* sW1Fl = p; p += 256 * 256;
  unsigned short* sW2Fh = p; p += 256 * 256;  unsigned short* sW2Fl = p; p += 256 * 256;
  unsigned short* dW1Fh = p; p += 512 * 256;  unsigned short* dW1Fl = p; p += 512 * 256;
  unsigned short* dW2Fh = p; p += 256 * 256;  unsigned short* dW2Fl = p; p += 256 * 256;
  unsigned short* catF  = p;   // (RT_N * 24 * 512) bf16 ≈ 400 MB

  auto WF = [&](const float* W, unsigned short* Fh, unsigned short* Fl, int K, int N) {
    int tot = K * N;
    wfrag_kernel<<<(tot + 255) / 256, 256, 0, stream>>>(W, Fh, Fl, K, N);
  };
  WF(eW1, eW1Fh, eW1Fl, 768, 256);
  WF(eW2, eW2Fh, eW2Fl, 256, 256);
  WF(sW1, sW1Fh, sW1Fl, 256, 256);
  WF(sW2, sW2Fh, sW2Fl, 256, 256);
  WF(dW1, dW1Fh, dW1Fl, 512, 256);
  WF(dW2, dW2Fh, dW2Fl, 256, 256);

  (void)hipMemsetAsync(out_mesh, 0, (size_t)NM_N * Hdim * sizeof(float), stream);

  // G: gather + convert + fragment-pack
  gather_frag<<<GB_N, 256, 0, stream>>>(g2m, gridf, meshf, src, dst, E_N, catF);

  // E': barrier-free streaming GEMM + LN + atomic scatter
  edge_gemm<<<NB_E, 512, 0, stream>>>(
      catF, E_N, eW1Fh, eW1Fl, eb1, eW2Fh, eW2Fl, eb2, eg, ebt, out_mesh, dst);

  // grid MLP: grid_new = grid + MLP(grid)
  mlp_mfma<1><<<(NG_N + 63) / 64, 256, 0, stream>>>(
      gridf, nullptr, nullptr, NG_N,
      sW1Fh, sW1Fl, sb1, sW2Fh, sW2Fl, sb2, sg, sbt,
      gridf, out_grid);

  // mesh MLP: mesh_new = mesh + MLP(cat[agg, mesh])
  mlp_mfma<2><<<(NM_N + 63) / 64, 256, 0, stream>>>(
      out_mesh, meshf, nullptr, NM_N,
      dW1Fh, dW1Fl, db1, dW2Fh, dW2Fl, db2, dg, dbt,
      meshf, out_mesh);
}

// Round 21
// 753.943 us; speedup vs baseline: 1.3260x; 1.3260x over previous
//
#include <hip/hip_runtime.h>

#define Hdim 256
static const int E_N  = 260640;
static const int NG_N = 65160;
static const int NM_N = 40962;

typedef __attribute__((ext_vector_type(8))) __bf16 bf16x8;
typedef __attribute__((ext_vector_type(8))) unsigned short u16x8;
typedef __attribute__((ext_vector_type(4))) float f32x4;

__device__ __forceinline__ unsigned short f2bf(float f) {
  unsigned u = __float_as_uint(f);
  u = (u + 0x7FFFu + ((u >> 16) & 1u)) >> 16;
  return (unsigned short)u;
}
__device__ __forceinline__ float bf2f(unsigned short h) {
  return __uint_as_float((unsigned)h << 16);
}
struct BfPair { unsigned short hi, lo; };
__device__ __forceinline__ BfPair split2(float f) {
  BfPair r;
  r.hi = f2bf(f);
  r.lo = f2bf(f - bf2f(r.hi));
  return r;
}
__device__ __forceinline__ BfPair split2t(float f) {
  unsigned u = __float_as_uint(f);
  BfPair r;
  r.hi = (unsigned short)(u >> 16);
  r.lo = f2bf(f - __uint_as_float(u & 0xffff0000u));
  return r;
}
__device__ __forceinline__ int hswz(int row) {
  return ((row & 7) << 3) ^ (((row >> 2) & 3) << 4);
}
__device__ __forceinline__ void bar_lds() {
  asm volatile("s_waitcnt lgkmcnt(0)" ::: "memory");
  __builtin_amdgcn_s_barrier();
}
// bijective XCD swizzle (m204): contiguous chunk per XCD, any nwg
__device__ __forceinline__ int xcd_swz(int bid, int nwg) {
  const int NX = 8;
  const int xcd = bid % NX;
  const int idx = bid / NX;
  const int q = nwg / NX, r = nwg % NX;
  const int base = xcd < r ? xcd * (q + 1) : r * (q + 1) + (xcd - r) * q;
  return base + idx;
}

// W [K][N=256] f32 -> fragment-major split-bf16 (R12-verified)
__global__ void wfrag_kernel(const float* __restrict__ W,
                             unsigned short* __restrict__ Fh,
                             unsigned short* __restrict__ Fl, int K, int N) {
  int i = blockIdx.x * 256 + threadIdx.x;
  if (i >= K * N) return;
  int k = i / N;
  int col = i - k * N;
  BfPair p = split2(W[i]);
  int t = k >> 5, rem = k & 31;
  int lg = rem >> 3, j = rem & 7;
  int cb = col >> 4, lr = col & 15;
  long o = ((long)(t * 16 + cb) * 64 + (lg * 16 + lr)) * 8 + j;
  Fh[o] = p.hi;
  Fl[o] = p.lo;
}

// edge (A3=false): union(ahi 18432, lnp 2048) + hh 32768 = 51.2 KB
// grid/mesh (A3=true): + alo 18432 = 69.6 KB -> 2 blocks/CU
template <bool A3>
struct SMem {
  union {
    unsigned short ahi[2][64][72];
    float lnp[4][64][2];
  } u;
  unsigned short alo[A3 ? 2 : 1][A3 ? 64 : 1][A3 ? 72 : 1];
  unsigned short hh[64 * 256];             // XOR-swizzled rows
};

// out = LN(silu(cat(segs)@W1+b1)@W2+b2)*g+b  [+residual | atomic scatter]
// layer1: A3 ? 3-product : 2-product; layer2: 2-product. Fragment-major W.
template <int NSEG, bool SCATTER, bool A3>
__launch_bounds__(256, 2)
__global__ void mlp_mfma(
    const float* s0, const float* s1, const float* s2,
    const int* __restrict__ i1, const int* __restrict__ i2, int M,
    const unsigned short* __restrict__ W1Fh, const unsigned short* __restrict__ W1Fl,
    const float* __restrict__ b1,
    const unsigned short* __restrict__ W2Fh, const unsigned short* __restrict__ W2Fl,
    const float* __restrict__ b2,
    const float* __restrict__ gamma, const float* __restrict__ beta,
    const float* residual, float* outp,
    float* agg, const int* __restrict__ scat, int nwg) {
  constexpr int K1 = NSEG * 256;
  constexpr int NT = K1 / 32;
  constexpr int NU = K1 / 64;
  __shared__ SMem<A3> sm;

  const int bid = SCATTER ? xcd_swz(blockIdx.x, nwg) : blockIdx.x;
  const int tid = threadIdx.x;
  const int w = tid >> 6;
  const int l = tid & 63;
  const int lr = l & 15;
  const int lg = l >> 4;
  const int colbase = w * 64 + lr;
  const long blockRow = (long)bid * 64;

  const long grow_s = blockRow + l;
  const long growc = grow_s < M ? grow_s : (long)(M - 1);
  const float* rp0 = s0 + growc * Hdim;
  const float* rp1 = nullptr;
  const float* rp2 = nullptr;
  if (NSEG >= 2) rp1 = s1 + (long)(i1 ? i1[growc] : (int)growc) * Hdim;
  if (NSEG >= 3) rp2 = s2 + (long)(i2 ? i2[growc] : (int)growc) * Hdim;

  auto aptr = [&](int m) -> const float* {
    const int seg = m >> 2;
    const float* rp = rp0;
    if (NSEG >= 2 && seg == 1) rp = rp1;
    if (NSEG >= 3 && seg == 2) rp = rp2;
    return rp + (m & 3) * 64 + w * 16;
  };

  auto loadA = [&](int m, float4* v) {
    const float* p = aptr(m);
#pragma unroll
    for (int i = 0; i < 4; ++i) v[i] = *(const float4*)(p + i * 4);
  };

  auto stageA = [&](int buf, const float4* v) {
    float in[16] = {v[0].x, v[0].y, v[0].z, v[0].w, v[1].x, v[1].y, v[1].z, v[1].w,
                    v[2].x, v[2].y, v[2].z, v[2].w, v[3].x, v[3].y, v[3].z, v[3].w};
    if constexpr (A3) {
      u16x8 th0, tl0, th1, tl1;
#pragma unroll
      for (int j = 0; j < 8; ++j) {
        BfPair p0 = split2t(in[j]);
        th0[j] = p0.hi; tl0[j] = p0.lo;
        BfPair p1 = split2t(in[j + 8]);
        th1[j] = p1.hi; tl1[j] = p1.lo;
      }
      *(u16x8*)&sm.u.ahi[buf][l][w * 16]     = th0;
      *(u16x8*)&sm.u.ahi[buf][l][w * 16 + 8] = th1;
      *(u16x8*)&sm.alo[buf][l][w * 16]       = tl0;
      *(u16x8*)&sm.alo[buf][l][w * 16 + 8]   = tl1;
    } else {
      u16x8 th0, th1;
#pragma unroll
      for (int j = 0; j < 8; ++j) {
        th0[j] = f2bf(in[j]);
        th1[j] = f2bf(in[j + 8]);
      }
      *(u16x8*)&sm.u.ahi[buf][l][w * 16]     = th0;
      *(u16x8*)&sm.u.ahi[buf][l][w * 16 + 8] = th1;
    }
  };

  auto loadB1 = [&](int t, bf16x8* bh, bf16x8* bl) {
#pragma unroll
    for (int n = 0; n < 4; ++n) {
      const long o = ((long)(t * 16 + w * 4 + n) * 64 + l) * 8;
      bh[n] = *(const bf16x8*)(W1Fh + o);
      bl[n] = *(const bf16x8*)(W1Fl + o);
    }
  };

  // ---------------- layer 1: cat(segs) @ W1 (R12 macro pipeline) ----------------
  f32x4 acc[4][4] = {};
  {
    float4 v[4];
    loadA(0, v);
    stageA(0, v);
  }
  float4 va[4], vb[4];               // A(u+1), A(u+2) in flight
  loadA(1 < NU ? 1 : NU - 1, va);
  bf16x8 bhc[4], blc[4];
  loadB1(0, bhc, blc);

  for (int u = 0; u < NU; ++u) {
    bar_lds();                       // buf[u&1] visible; no vmcnt drain
    loadA(u + 2 < NU ? u + 2 : NU - 1, vb);
    // ---- k-step s=0 (t = 2u) ----
    bf16x8 bhn[4], bln[4];
    loadB1(2 * u + 1 < NT ? 2 * u + 1 : NT - 1, bhn, bln);
    bf16x8 ah[4], al[4];
#pragma unroll
    for (int rb = 0; rb < 4; ++rb) {
      ah[rb] = *(const bf16x8*)&sm.u.ahi[u & 1][rb * 16 + lr][lg * 8];
      if constexpr (A3) al[rb] = *(const bf16x8*)&sm.alo[u & 1][rb * 16 + lr][lg * 8];
    }
    __builtin_amdgcn_s_setprio(1);
#pragma unroll
    for (int rb = 0; rb < 4; ++rb)
#pragma unroll
      for (int n = 0; n < 4; ++n) {
        acc[rb][n] = __builtin_amdgcn_mfma_f32_16x16x32_bf16(ah[rb], bhc[n], acc[rb][n], 0, 0, 0);
        acc[rb][n] = __builtin_amdgcn_mfma_f32_16x16x32_bf16(ah[rb], blc[n], acc[rb][n], 0, 0, 0);
        if constexpr (A3)
          acc[rb][n] = __builtin_amdgcn_mfma_f32_16x16x32_bf16(al[rb], bhc[n], acc[rb][n], 0, 0, 0);
      }
    __builtin_amdgcn_s_setprio(0);
    // ---- k-step s=1 (t = 2u+1) ----
    bf16x8 bh2[4], bl2[4];
    loadB1(2 * u + 2 < NT ? 2 * u + 2 : NT - 1, bh2, bl2);
#pragma unroll
    for (int rb = 0; rb < 4; ++rb) {
      ah[rb] = *(const bf16x8*)&sm.u.ahi[u & 1][rb * 16 + lr][32 + lg * 8];
      if constexpr (A3) al[rb] = *(const bf16x8*)&sm.alo[u & 1][rb * 16 + lr][32 + lg * 8];
    }
    __builtin_amdgcn_s_setprio(1);
#pragma unroll
    for (int rb = 0; rb < 4; ++rb)
#pragma unroll
      for (int n = 0; n < 4; ++n) {
        acc[rb][n] = __builtin_amdgcn_mfma_f32_16x16x32_bf16(ah[rb], bhn[n], acc[rb][n], 0, 0, 0);
        acc[rb][n] = __builtin_amdgcn_mfma_f32_16x16x32_bf16(ah[rb], bln[n], acc[rb][n], 0, 0, 0);
        if constexpr (A3)
          acc[rb][n] = __builtin_amdgcn_mfma_f32_16x16x32_bf16(al[rb], bhn[n], acc[rb][n], 0, 0, 0);
      }
    __builtin_amdgcn_s_setprio(0);
    // ---- stage A(u+1) ----
    if (u + 1 < NU) stageA((u + 1) & 1, va);
#pragma unroll
    for (int i = 0; i < 4; ++i) va[i] = vb[i];
#pragma unroll
    for (int n = 0; n < 4; ++n) { bhc[n] = bh2[n]; blc[n] = bl2[n]; }
  }

  // B2(0) prefetch early
  bf16x8 b2hc[4], b2lc[4];
#pragma unroll
  for (int n = 0; n < 4; ++n) {
    const long o = ((long)(w * 4 + n) * 64 + l) * 8;
    b2hc[n] = *(const bf16x8*)(W2Fh + o);
    b2lc[n] = *(const bf16x8*)(W2Fl + o);
  }

  // ---------------- bias1 + SiLU -> h (bf16 hi, XOR-swizzled) ----------------
  float bb1[4];
#pragma unroll
  for (int n = 0; n < 4; ++n) bb1[n] = b1[colbase + n * 16];
#pragma unroll
  for (int rb = 0; rb < 4; ++rb) {
#pragma unroll
    for (int n = 0; n < 4; ++n) {
      const int col = colbase + n * 16;
#pragma unroll
      for (int r = 0; r < 4; ++r) {
        const int row = rb * 16 + lg * 4 + r;
        float v = acc[rb][n][r] + bb1[n];
        v = v / (1.0f + __expf(-v));
        sm.hh[row * 256 + (col ^ hswz(row))] = f2bf(v);
      }
    }
  }
  bar_lds();

  // ---------------- layer 2: h @ W2 (2-product, no barriers) ----------------
  f32x4 acc2[4][4] = {};
  for (int ks = 0; ks < 8; ++ks) {
    const int kn = (ks + 1 < 8) ? ks + 1 : ks;
    bf16x8 b2hn[4], b2ln[4];
#pragma unroll
    for (int n = 0; n < 4; ++n) {
      const long o = ((long)(kn * 16 + w * 4 + n) * 64 + l) * 8;
      b2hn[n] = *(const bf16x8*)(W2Fh + o);
      b2ln[n] = *(const bf16x8*)(W2Fl + o);
    }
    bf16x8 ah[4];
#pragma unroll
    for (int rb = 0; rb < 4; ++rb) {
      const int row = rb * 16 + lr;
      ah[rb] = *(const bf16x8*)&sm.hh[row * 256 + ((ks * 32 + lg * 8) ^ hswz(row))];
    }
    __builtin_amdgcn_s_setprio(1);
#pragma unroll
    for (int rb = 0; rb < 4; ++rb)
#pragma unroll
      for (int n = 0; n < 4; ++n) {
        acc2[rb][n] = __builtin_amdgcn_mfma_f32_16x16x32_bf16(ah[rb], b2hc[n], acc2[rb][n], 0, 0, 0);
        acc2[rb][n] = __builtin_amdgcn_mfma_f32_16x16x32_bf16(ah[rb], b2lc[n], acc2[rb][n], 0, 0, 0);
      }
    __builtin_amdgcn_s_setprio(0);
#pragma unroll
    for (int n = 0; n < 4; ++n) { b2hc[n] = b2hn[n]; b2lc[n] = b2ln[n]; }
  }
  __syncthreads();   // hh reads done; ahi/lnp union re-used below

  // ---------------- LayerNorm in registers (two-pass) + epilogue ----------------
  float bb2[4], gmv[4], btv[4];
#pragma unroll
  for (int n = 0; n < 4; ++n) {
    const int c = colbase + n * 16;
    bb2[n] = b2[c];
    gmv[n] = gamma[c];
    btv[n] = beta[c];
  }
  float psum[16];
#pragma unroll
  for (int rb = 0; rb < 4; ++rb)
#pragma unroll
    for (int r = 0; r < 4; ++r) {
      float s = 0.f;
#pragma unroll
      for (int n = 0; n < 4; ++n) s += acc2[rb][n][r] + bb2[n];
      psum[rb * 4 + r] = s;
    }
#pragma unroll
  for (int i = 0; i < 16; ++i) {
    psum[i] += __shfl_xor(psum[i], 1, 64);
    psum[i] += __shfl_xor(psum[i], 2, 64);
    psum[i] += __shfl_xor(psum[i], 4, 64);
    psum[i] += __shfl_xor(psum[i], 8, 64);
  }
  if (lr == 0) {
#pragma unroll
    for (int rb = 0; rb < 4; ++rb)
#pragma unroll
      for (int r = 0; r < 4; ++r)
        sm.u.lnp[w][rb * 16 + lg * 4 + r][0] = psum[rb * 4 + r];
  }
  __syncthreads();
  float mu[16];
#pragma unroll
  for (int rb = 0; rb < 4; ++rb)
#pragma unroll
    for (int r = 0; r < 4; ++r) {
      const int row = rb * 16 + lg * 4 + r;
      mu[rb * 4 + r] = (sm.u.lnp[0][row][0] + sm.u.lnp[1][row][0] +
                        sm.u.lnp[2][row][0] + sm.u.lnp[3][row][0]) * (1.0f / 256.0f);
    }
  float psq[16];
#pragma unroll
  for (int rb = 0; rb < 4; ++rb)
#pragma unroll
    for (int r = 0; r < 4; ++r) {
      float s = 0.f;
#pragma unroll
      for (int n = 0; n < 4; ++n) {
        const float d = acc2[rb][n][r] + bb2[n] - mu[rb * 4 + r];
        s += d * d;
      }
      psq[rb * 4 + r] = s;
    }
#pragma unroll
  for (int i = 0; i < 16; ++i) {
    psq[i] += __shfl_xor(psq[i], 1, 64);
    psq[i] += __shfl_xor(psq[i], 2, 64);
    psq[i] += __shfl_xor(psq[i], 4, 64);
    psq[i] += __shfl_xor(psq[i], 8, 64);
  }
  if (lr == 0) {
#pragma unroll
    for (int rb = 0; rb < 4; ++rb)
#pragma unroll
      for (int r = 0; r < 4; ++r)
        sm.u.lnp[w][rb * 16 + lg * 4 + r][1] = psq[rb * 4 + r];
  }
  __syncthreads();
#pragma unroll
  for (int rb = 0; rb < 4; ++rb) {
#pragma unroll
    for (int r = 0; r < 4; ++r) {
      const int row = rb * 16 + lg * 4 + r;
      const long grow = blockRow + row;
      if (grow >= M) continue;
      const float var = (sm.u.lnp[0][row][1] + sm.u.lnp[1][row][1] +
                         sm.u.lnp[2][row][1] + sm.u.lnp[3][row][1]) * (1.0f / 256.0f);
      const float rstd = 1.0f / sqrtf(var + 1e-5f);
      const float m = mu[rb * 4 + r];
      if constexpr (SCATTER) {
        const int d = scat[grow];
        float* ap = agg + (long)d * Hdim;
#pragma unroll
        for (int n = 0; n < 4; ++n) {
          const int c = colbase + n * 16;
          atomicAdd(ap + c, (acc2[rb][n][r] + bb2[n] - m) * rstd * gmv[n] + btv[n]);
        }
      } else {
        const long o = grow * Hdim;
#pragma unroll
        for (int n = 0; n < 4; ++n) {
          const int c = colbase + n * 16;
          outp[o + c] = (acc2[rb][n][r] + bb2[n] - m) * rstd * gmv[n] + btv[n] + residual[o + c];
        }
      }
    }
  }
}

extern "C" void kernel_launch(void* const* d_in, const int* in_sizes, int n_in,
                              void* d_out, int out_size, void* d_ws, size_t ws_size,
                              hipStream_t stream) {
  const float* g2m   = (const float*)d_in[0];
  const float* gridf = (const float*)d_in[1];
  const float* meshf = (const float*)d_in[2];
  const int*   src   = (const int*)d_in[3];
  const int*   dst   = (const int*)d_in[4];
  const float* eW1 = (const float*)d_in[5];  const float* eb1 = (const float*)d_in[6];
  const float* eW2 = (const float*)d_in[7];  const float* eb2 = (const float*)d_in[8];
  const float* eg  = (const float*)d_in[9];  const float* ebt = (const float*)d_in[10];
  const float* sW1 = (const float*)d_in[11]; const float* sb1 = (const float*)d_in[12];
  const float* sW2 = (const float*)d_in[13]; const float* sb2 = (const float*)d_in[14];
  const float* sg  = (const float*)d_in[15]; const float* sbt = (const float*)d_in[16];
  const float* dW1 = (const float*)d_in[17]; const float* db1 = (const float*)d_in[18];
  const float* dW2 = (const float*)d_in[19]; const float* db2 = (const float*)d_in[20];
  const float* dg  = (const float*)d_in[21]; const float* dbt = (const float*)d_in[22];

  float* out_grid = (float*)d_out;
  float* out_mesh = out_grid + (long)NG_N * Hdim;

  unsigned short* p = (unsigned short*)d_ws;
  unsigned short* eW1Fh = p; p += 768 * 256;  unsigned short* eW1Fl = p; p += 768 * 256;
  unsigned short* eW2Fh = p; p += 256 * 256;  unsigned short* eW2Fl = p; p += 256 * 256;
  unsigned short* sW1Fh = p; p += 256 * 256;  unsigned short* sW1Fl = p; p += 256 * 256;
  unsigned short* sW2Fh = p; p += 256 * 256;  unsigned short* sW2Fl = p; p += 256 * 256;
  unsigned short* dW1Fh = p; p += 512 * 256;  unsigned short* dW1Fl = p; p += 512 * 256;
  unsigned short* dW2Fh = p; p += 256 * 256;  unsigned short* dW2Fl = p; p += 256 * 256;

  auto WF = [&](const float* W, unsigned short* Fh, unsigned short* Fl, int K, int N) {
    int tot = K * N;
    wfrag_kernel<<<(tot + 255) / 256, 256, 0, stream>>>(W, Fh, Fl, K, N);
  };
  WF(eW1, eW1Fh, eW1Fl, 768, 256);
  WF(eW2, eW2Fh, eW2Fl, 256, 256);
  WF(sW1, sW1Fh, sW1Fl, 256, 256);
  WF(sW2, sW2Fh, sW2Fl, 256, 256);
  WF(dW1, dW1Fh, dW1Fl, 512, 256);
  WF(dW2, dW2Fh, dW2Fl, 256, 256);

  (void)hipMemsetAsync(out_mesh, 0, (size_t)NM_N * Hdim * sizeof(float), stream);

  const int nwgE = (E_N + 63) / 64;
  mlp_mfma<3, true, false><<<nwgE, 256, 0, stream>>>(
      g2m, gridf, meshf, src, dst, E_N,
      eW1Fh, eW1Fl, eb1, eW2Fh, eW2Fl, eb2, eg, ebt,
      nullptr, nullptr, out_mesh, dst, nwgE);

  mlp_mfma<1, false, true><<<(NG_N + 63) / 64, 256, 0, stream>>>(
      gridf, nullptr, nullptr, nullptr, nullptr, NG_N,
      sW1Fh, sW1Fl, sb1, sW2Fh, sW2Fl, sb2, sg, sbt,
      gridf, out_grid, nullptr, nullptr, 0);

  mlp_mfma<2, false, true><<<(NM_N + 63) / 64, 256, 0, stream>>>(
      out_mesh, meshf, nullptr, nullptr, nullptr, NM_N,
      dW1Fh, dW1Fl, db1, dW2Fh, dW2Fl, db2, dg, dbt,
      meshf, out_mesh, nullptr, nullptr, 0);
}